// Round 1
// 307.259 us; speedup vs baseline: 1.0052x; 1.0052x over previous
//
#include <hip/hip_runtime.h>

// SpectralConv: B=8, H=256, W=256, C=64, modes 16x16, WIDTH=64, W_SCALE=0.02
// Round 3:
//  - Stage A rewritten: one (b,h) row per block, x staged global->LDS via
//    global_load_lds double-buffer (each x byte fetched from HBM exactly once),
//    all 16 ky per block, w-half partials combined via __shfl_xor(.,16).
//    18 KiB LDS, 8 blocks/CU.
//  - Stages D+E fused: Zc slice (8 KiB per (b,w)) lives in LDS, never touches
//    HBM. om (1 MiB) is read from L2. One fewer dispatch, -48 MiB HBM traffic.
//  - Stages B, C unchanged.

#define NB 8
#define NH 256
#define NW 256
#define NC 64
#define NM 16
#define NO 64

// async global->LDS, 16 bytes per lane. LDS dest semantics (m97/m104):
// wave-uniform base + lane*16; pass a wave-uniform LDS pointer.
__device__ __forceinline__ void gload16(const float* g, float* l) {
  __builtin_amdgcn_global_load_lds(
      (const __attribute__((address_space(1))) void*)g,
      (__attribute__((address_space(3))) void*)l, 16, 0, 0);
}

// ---------------- Stage A: G[b][ky][h][i] = sum_w x[b,h,w,i] e^{-2pi i ky w/256}
// grid 2048 = b(8) x h(256); 256 thr: i4 = t&15, wh = (t>>4)&1, kyp = t>>5 (2 ky each).
// Each thread accumulates its 2 ky over its w-half of every 32-w chunk; halves
// combined with __shfl_xor(16) (partner lane is in the same wave).
__global__ __launch_bounds__(256) void k_dft_w(const float* __restrict__ x,
                                               float* __restrict__ Gr, float* __restrict__ Gi) {
  __shared__ float2 cs[256];
  __shared__ float xs[2][2048];  // double buffer: 2 x (32 w x 64 c) = 2 x 8 KiB
  const int t = threadIdx.x;
  {
    float s, c;
    sincospif((float)t * (1.0f / 128.0f), &s, &c);
    cs[t] = make_float2(c, s);
  }
  const int b = blockIdx.x >> 8;
  const int h = blockIdx.x & 255;
  const float* row = x + (size_t)(b * NH + h) * (NW * NC);  // 64 KiB contiguous

  const int wv = t >> 6;  // wave id, uniform per wave
  // prologue: stage chunk 0 (8 KiB = 2 rounds of 256 lanes x 16 B)
  {
    const float* g0 = row + t * 4;
    gload16(g0, &xs[0][wv * 256]);
    gload16(g0 + 1024, &xs[0][1024 + wv * 256]);
  }

  const int i4 = t & 15;
  const int wh = (t >> 4) & 1;
  const int kyp = t >> 5;  // 0..7
  const int ky0 = kyp * 2, ky1 = ky0 + 1;

  __syncthreads();  // cs ready + chunk 0 landed (barrier drains vmcnt)

  const float2 s0v = cs[ky0], s1v = cs[ky1];
  const float s0r = s0v.x, s0i = -s0v.y, s1r = s1v.x, s1i = -s1v.y;

  float4 ar0 = {0, 0, 0, 0}, ai0 = {0, 0, 0, 0}, ar1 = {0, 0, 0, 0}, ai1 = {0, 0, 0, 0};
  int buf = 0;
  for (int c = 0; c < 8; ++c) {
    if (c < 7) {  // issue next-chunk async loads; they fly during compute
      const float* g0 = row + (c + 1) * 2048 + t * 4;
      gload16(g0, &xs[buf ^ 1][wv * 256]);
      gload16(g0 + 1024, &xs[buf ^ 1][1024 + wv * 256]);
    }
    const int w0 = c * 32 + wh * 16;
    const float2 u0 = cs[(ky0 * w0) & 255];
    const float2 u1 = cs[(ky1 * w0) & 255];
    float t0r = u0.x, t0i = -u0.y, t1r = u1.x, t1i = -u1.y;
    const float* xb = &xs[buf][wh * 1024 + i4 * 4];
#pragma unroll
    for (int ww = 0; ww < 16; ++ww) {
      const float4 xv = *(const float4*)(xb + ww * 64);
      ar0.x += t0r * xv.x; ar0.y += t0r * xv.y; ar0.z += t0r * xv.z; ar0.w += t0r * xv.w;
      ai0.x += t0i * xv.x; ai0.y += t0i * xv.y; ai0.z += t0i * xv.z; ai0.w += t0i * xv.w;
      ar1.x += t1r * xv.x; ar1.y += t1r * xv.y; ar1.z += t1r * xv.z; ar1.w += t1r * xv.w;
      ai1.x += t1i * xv.x; ai1.y += t1i * xv.y; ai1.z += t1i * xv.z; ai1.w += t1i * xv.w;
      const float n0r = t0r * s0r - t0i * s0i, n0i = t0r * s0i + t0i * s0r;
      const float n1r = t1r * s1r - t1i * s1i, n1i = t1r * s1i + t1i * s1r;
      t0r = n0r; t0i = n0i; t1r = n1r; t1i = n1i;
    }
    __syncthreads();  // next chunk landed; all waves done reading xs[buf]
    buf ^= 1;
  }

  // combine the two w-halves: partner lane = lane ^ 16 (same wave: wh is bit 4)
#define RED4(v)                                                         \
  v.x += __shfl_xor(v.x, 16); v.y += __shfl_xor(v.y, 16);               \
  v.z += __shfl_xor(v.z, 16); v.w += __shfl_xor(v.w, 16);
  RED4(ar0) RED4(ai0) RED4(ar1) RED4(ai1)
#undef RED4

  if (wh == 0) {
    const size_t g0 = ((size_t)(b * NM + ky0) * NH + h) * NC + i4 * 4;
    const size_t g1 = ((size_t)(b * NM + ky1) * NH + h) * NC + i4 * 4;
    *(float4*)(Gr + g0) = ar0; *(float4*)(Gi + g0) = ai0;
    *(float4*)(Gr + g1) = ar1; *(float4*)(Gi + g1) = ai1;
  }
}

// ---------------- Stage B: Xp[hc][kx][ky][b][i] = sum_{h in chunk} e^{-2pi i kx h/256} G[b][ky][h][i]
// grid 1024 = b(8) x ky(16) x hc(8); 256 thr: i4 = t&15, kx = t>>4   (unchanged)
__global__ __launch_bounds__(256) void k_dft_h(const float* __restrict__ Gr, const float* __restrict__ Gi,
                                               float* __restrict__ Xpr, float* __restrict__ Xpi) {
  __shared__ float2 cs[256];
  __shared__ float gr[32 * 64];
  __shared__ float gi[32 * 64];
  const int t = threadIdx.x;
  {
    float s, c;
    sincospif((float)t * (1.0f / 128.0f), &s, &c);
    cs[t] = make_float2(c, s);
  }
  const int b = blockIdx.x >> 7;
  const int ky = (blockIdx.x >> 3) & 15;
  const int hc = blockIdx.x & 7;
  const float* grs = Gr + ((size_t)(b * NM + ky) * NH + hc * 32) * NC;
  const float* gis = Gi + ((size_t)(b * NM + ky) * NH + hc * 32) * NC;
#pragma unroll
  for (int r = 0; r < 2; ++r) {
    ((float4*)gr)[r * 256 + t] = ((const float4*)grs)[r * 256 + t];
    ((float4*)gi)[r * 256 + t] = ((const float4*)gis)[r * 256 + t];
  }
  __syncthreads();
  const int i4 = t & 15;
  const int kx = t >> 4;
  float4 xr = {0, 0, 0, 0}, xi = {0, 0, 0, 0};
  const float2 sv = cs[kx];
  const float str = sv.x, sti = -sv.y;
  const float2 tv = cs[(kx * hc * 32) & 255];
  float twr = tv.x, twi = -tv.y;
#pragma unroll 4
  for (int hh = 0; hh < 32; ++hh) {
    const float4 g_r = *(const float4*)&gr[hh * 64 + i4 * 4];
    const float4 g_i = *(const float4*)&gi[hh * 64 + i4 * 4];
    xr.x += twr * g_r.x - twi * g_i.x;
    xr.y += twr * g_r.y - twi * g_i.y;
    xr.z += twr * g_r.z - twi * g_i.z;
    xr.w += twr * g_r.w - twi * g_i.w;
    xi.x += twr * g_i.x + twi * g_r.x;
    xi.y += twr * g_i.y + twi * g_r.y;
    xi.z += twr * g_i.z + twi * g_r.z;
    xi.w += twr * g_i.w + twi * g_r.w;
    const float nr = twr * str - twi * sti;
    const float ni = twr * sti + twi * str;
    twr = nr; twi = ni;
  }
  const size_t o = ((size_t)((hc * NM + kx) * NM + ky) * NB + b) * NC + i4 * 4;
  *(float4*)(Xpr + o) = xr;
  *(float4*)(Xpi + o) = xi;
}

// ---------------- Stage C: om[b][kx][ky][o] = scale * sum_i (sum_hc Xp) * (wr + i wi)[kx][ky][i][o]
// grid 512 = kx(16) x ky(16) x oh(2); 256 thr: o = t&31, b = t>>5   (unchanged)
__global__ __launch_bounds__(256) void k_mix(const float* __restrict__ Xpr, const float* __restrict__ Xpi,
                                             const float* __restrict__ w_real, const float* __restrict__ w_imag,
                                             float2* __restrict__ om) {
  __shared__ float wr_s[64 * 32];
  __shared__ float wi_s[64 * 32];
  __shared__ float2 xc[8 * 64];
  const int t = threadIdx.x;
  const int kx = blockIdx.x >> 5;
  const int ky = (blockIdx.x >> 1) & 15;
  const int oh = blockIdx.x & 1;
  const size_t wb = (size_t)(kx * NM + ky) * 4096 + oh * 32;
#pragma unroll
  for (int r = 0; r < 2; ++r) {
    const int idx = r * 256 + t;  // 0..511
    const int i = idx >> 3, f = idx & 7;
    *(float4*)&wr_s[i * 32 + f * 4] = *(const float4*)(w_real + wb + (size_t)i * 64 + f * 4);
    *(float4*)&wi_s[i * 32 + f * 4] = *(const float4*)(w_imag + wb + (size_t)i * 64 + f * 4);
  }
#pragma unroll
  for (int r = 0; r < 2; ++r) {
    const int idx = r * 256 + t;  // idx = b*64 + i
    const size_t base = (size_t)(kx * NM + ky) * 512 + idx;
    float sr = 0.f, si = 0.f;
#pragma unroll
    for (int hc = 0; hc < 8; ++hc) {
      sr += Xpr[base + (size_t)hc * 131072];
      si += Xpi[base + (size_t)hc * 131072];
    }
    xc[idx] = make_float2(sr, si);
  }
  __syncthreads();
  const int o = t & 31;
  const int b = t >> 5;
  float r0 = 0.f, i0 = 0.f;
#pragma unroll 8
  for (int i = 0; i < 64; ++i) {
    const float2 xv = xc[b * 64 + i];
    const float wrv = wr_s[i * 32 + o];
    const float wiv = wi_s[i * 32 + o];
    r0 += xv.x * wrv - xv.y * wiv;
    i0 += xv.x * wiv + xv.y * wrv;
  }
  const float sc = (ky == 0 ? 1.0f : 2.0f) * (0.02f / 65536.0f);
  om[((size_t)(b * NM + kx) * NM + ky) * NO + oh * 32 + o] = make_float2(r0 * sc, i0 * sc);
}

// ---------------- Fused Stage D+E:
// Phase 1: Zs[kx][o] = sum_ky om[b][kx][ky][o] e^{+2pi i ky w/256}   (into LDS)
// Phase 2: out[b][h][w][o] = sum_kx Re( Zs[kx][o] e^{+2pi i kx h/256} )
// grid 2048 = b(8) x w(256); 256 thr.
// Phase 1 mapping: kx = t>>4 (16), og = t&15 (4 o each).
// Phase 2 mapping: i4 = t&15 (4 o), hg = t>>4 (16), hh-loop -> 256 h per block.
#define ZLD 72  // LDS stride (floats) per kx: 16-B aligned, breaks 256-B bank repeat
__global__ __launch_bounds__(256) void k_idft_we(const float2* __restrict__ om, float* __restrict__ out) {
  __shared__ float2 cs[256];
  __shared__ float zre[NM * ZLD];
  __shared__ float zim[NM * ZLD];
  const int t = threadIdx.x;
  {
    float s, c;
    sincospif((float)t * (1.0f / 128.0f), &s, &c);
    cs[t] = make_float2(c, s);
  }
  const int b = blockIdx.x >> 8;
  const int w = blockIdx.x & 255;
  __syncthreads();  // cs ready

  // ---- phase 1: inverse DFT over ky for this w
  {
    const int kx = t >> 4;
    const int og = t & 15;
    const float2* mp = om + ((size_t)(b * NM + kx) * NM) * NO + og * 4;
    float zr[4] = {0, 0, 0, 0}, zi[4] = {0, 0, 0, 0};
    const float2 st = cs[w];
    float twr = 1.0f, twi = 0.0f;
#pragma unroll
    for (int ky = 0; ky < NM; ++ky) {
      const float2 m0 = mp[(size_t)ky * NO + 0];
      const float2 m1 = mp[(size_t)ky * NO + 1];
      const float2 m2 = mp[(size_t)ky * NO + 2];
      const float2 m3 = mp[(size_t)ky * NO + 3];
      zr[0] += twr * m0.x - twi * m0.y; zi[0] += twr * m0.y + twi * m0.x;
      zr[1] += twr * m1.x - twi * m1.y; zi[1] += twr * m1.y + twi * m1.x;
      zr[2] += twr * m2.x - twi * m2.y; zi[2] += twr * m2.y + twi * m2.x;
      zr[3] += twr * m3.x - twi * m3.y; zi[3] += twr * m3.y + twi * m3.x;
      const float nr = twr * st.x - twi * st.y;
      const float ni = twr * st.y + twi * st.x;
      twr = nr; twi = ni;
    }
    *(float4*)&zre[kx * ZLD + og * 4] = make_float4(zr[0], zr[1], zr[2], zr[3]);
    *(float4*)&zim[kx * ZLD + og * 4] = make_float4(zi[0], zi[1], zi[2], zi[3]);
  }
  __syncthreads();

  // ---- phase 2: inverse DFT over kx, real part, all 256 h for this (b,w)
  const int i4 = t & 15;
  const int hg = t >> 4;
#pragma unroll
  for (int hh = 0; hh < 2; ++hh) {
    const int h0 = hh * 128 + hg * 8;
    float4 acc[8];
#pragma unroll
    for (int j = 0; j < 8; ++j) acc[j] = make_float4(0, 0, 0, 0);
#pragma unroll 4
    for (int kx = 0; kx < 16; ++kx) {
      const float4 zr4 = *(const float4*)&zre[kx * ZLD + i4 * 4];
      const float4 zi4 = *(const float4*)&zim[kx * ZLD + i4 * 4];
      const float2 t0 = cs[(kx * h0) & 255];
      const float2 st = cs[kx];
      float twr = t0.x, twi = t0.y;
#pragma unroll
      for (int j = 0; j < 8; ++j) {
        acc[j].x += twr * zr4.x - twi * zi4.x;
        acc[j].y += twr * zr4.y - twi * zi4.y;
        acc[j].z += twr * zr4.z - twi * zi4.z;
        acc[j].w += twr * zr4.w - twi * zi4.w;
        const float nr = twr * st.x - twi * st.y;
        const float ni = twr * st.y + twi * st.x;
        twr = nr; twi = ni;
      }
    }
    float* ob = out + (((size_t)(b * NH) + h0) * NW + w) * NO + i4 * 4;
#pragma unroll
    for (int j = 0; j < 8; ++j) {
      *(float4*)(ob + (size_t)j * (NW * NO)) = acc[j];
    }
  }
}

extern "C" void kernel_launch(void* const* d_in, const int* in_sizes, int n_in,
                              void* d_out, int out_size, void* d_ws, size_t ws_size,
                              hipStream_t stream) {
  const float* x = (const float*)d_in[0];
  const float* w_real = (const float*)d_in[1];
  const float* w_imag = (const float*)d_in[2];
  float* out = (float*)d_out;
  char* ws = (char*)d_ws;

  // workspace layout (bytes), total 25 MiB + 1 MiB (Zc eliminated — lives in LDS):
  float* Gr = (float*)(ws);                 // 8 MiB  [b][ky][h][i]
  float* Gi = (float*)(ws + 8388608);       // 8 MiB
  float* Xpr = (float*)(ws + 16777216);     // 4 MiB  [hc][kx][ky][b][i]
  float* Xpi = (float*)(ws + 20971520);     // 4 MiB
  float2* om = (float2*)(ws + 25165824);    // 1 MiB  [b][kx][ky][o]

  k_dft_w<<<dim3(2048), dim3(256), 0, stream>>>(x, Gr, Gi);
  k_dft_h<<<dim3(1024), dim3(256), 0, stream>>>(Gr, Gi, Xpr, Xpi);
  k_mix<<<dim3(512), dim3(256), 0, stream>>>(Xpr, Xpi, w_real, w_imag, om);
  k_idft_we<<<dim3(2048), dim3(256), 0, stream>>>(om, out);
}

// Round 2
// 284.576 us; speedup vs baseline: 1.0853x; 1.0797x over previous
//
#include <hip/hip_runtime.h>

// SpectralConv: B=8, H=256, W=256, C=64, modes 16x16, WIDTH=64, W_SCALE=0.02
// Round 4:
//  - Stage DE phase 2: h-conjugate symmetry. out[h] and out[256-h] share
//    zr*cos / zi*sin products -> accumulate accA = sum zr*cos, accB = sum
//    zi*sin per (h,256-h) pair, form both outputs by add/sub. Phase-2 FMA
//    count halves (VALU ~20.5us -> ~10.5us, now well under the 20.6us
//    write floor). h=0: accB==0 automatically; h=128: predicated sum +-zr.
//  - Stages A, B, C unchanged (A is at its HBM read floor; B/C are ~5us each).

#define NB 8
#define NH 256
#define NW 256
#define NC 64
#define NM 16
#define NO 64

// async global->LDS, 16 bytes per lane. LDS dest semantics (m97/m104):
// wave-uniform base + lane*16; pass a wave-uniform LDS pointer.
__device__ __forceinline__ void gload16(const float* g, float* l) {
  __builtin_amdgcn_global_load_lds(
      (const __attribute__((address_space(1))) void*)g,
      (__attribute__((address_space(3))) void*)l, 16, 0, 0);
}

// ---------------- Stage A: G[b][ky][h][i] = sum_w x[b,h,w,i] e^{-2pi i ky w/256}
// grid 2048 = b(8) x h(256); 256 thr: i4 = t&15, wh = (t>>4)&1, kyp = t>>5 (2 ky each).
__global__ __launch_bounds__(256) void k_dft_w(const float* __restrict__ x,
                                               float* __restrict__ Gr, float* __restrict__ Gi) {
  __shared__ float2 cs[256];
  __shared__ float xs[2][2048];  // double buffer: 2 x (32 w x 64 c) = 2 x 8 KiB
  const int t = threadIdx.x;
  {
    float s, c;
    sincospif((float)t * (1.0f / 128.0f), &s, &c);
    cs[t] = make_float2(c, s);
  }
  const int b = blockIdx.x >> 8;
  const int h = blockIdx.x & 255;
  const float* row = x + (size_t)(b * NH + h) * (NW * NC);  // 64 KiB contiguous

  const int wv = t >> 6;  // wave id, uniform per wave
  {
    const float* g0 = row + t * 4;
    gload16(g0, &xs[0][wv * 256]);
    gload16(g0 + 1024, &xs[0][1024 + wv * 256]);
  }

  const int i4 = t & 15;
  const int wh = (t >> 4) & 1;
  const int kyp = t >> 5;  // 0..7
  const int ky0 = kyp * 2, ky1 = ky0 + 1;

  __syncthreads();  // cs ready + chunk 0 landed

  const float2 s0v = cs[ky0], s1v = cs[ky1];
  const float s0r = s0v.x, s0i = -s0v.y, s1r = s1v.x, s1i = -s1v.y;

  float4 ar0 = {0, 0, 0, 0}, ai0 = {0, 0, 0, 0}, ar1 = {0, 0, 0, 0}, ai1 = {0, 0, 0, 0};
  int buf = 0;
  for (int c = 0; c < 8; ++c) {
    if (c < 7) {
      const float* g0 = row + (c + 1) * 2048 + t * 4;
      gload16(g0, &xs[buf ^ 1][wv * 256]);
      gload16(g0 + 1024, &xs[buf ^ 1][1024 + wv * 256]);
    }
    const int w0 = c * 32 + wh * 16;
    const float2 u0 = cs[(ky0 * w0) & 255];
    const float2 u1 = cs[(ky1 * w0) & 255];
    float t0r = u0.x, t0i = -u0.y, t1r = u1.x, t1i = -u1.y;
    const float* xb = &xs[buf][wh * 1024 + i4 * 4];
#pragma unroll
    for (int ww = 0; ww < 16; ++ww) {
      const float4 xv = *(const float4*)(xb + ww * 64);
      ar0.x += t0r * xv.x; ar0.y += t0r * xv.y; ar0.z += t0r * xv.z; ar0.w += t0r * xv.w;
      ai0.x += t0i * xv.x; ai0.y += t0i * xv.y; ai0.z += t0i * xv.z; ai0.w += t0i * xv.w;
      ar1.x += t1r * xv.x; ar1.y += t1r * xv.y; ar1.z += t1r * xv.z; ar1.w += t1r * xv.w;
      ai1.x += t1i * xv.x; ai1.y += t1i * xv.y; ai1.z += t1i * xv.z; ai1.w += t1i * xv.w;
      const float n0r = t0r * s0r - t0i * s0i, n0i = t0r * s0i + t0i * s0r;
      const float n1r = t1r * s1r - t1i * s1i, n1i = t1r * s1i + t1i * s1r;
      t0r = n0r; t0i = n0i; t1r = n1r; t1i = n1i;
    }
    __syncthreads();
    buf ^= 1;
  }

#define RED4(v)                                                         \
  v.x += __shfl_xor(v.x, 16); v.y += __shfl_xor(v.y, 16);               \
  v.z += __shfl_xor(v.z, 16); v.w += __shfl_xor(v.w, 16);
  RED4(ar0) RED4(ai0) RED4(ar1) RED4(ai1)
#undef RED4

  if (wh == 0) {
    const size_t g0 = ((size_t)(b * NM + ky0) * NH + h) * NC + i4 * 4;
    const size_t g1 = ((size_t)(b * NM + ky1) * NH + h) * NC + i4 * 4;
    *(float4*)(Gr + g0) = ar0; *(float4*)(Gi + g0) = ai0;
    *(float4*)(Gr + g1) = ar1; *(float4*)(Gi + g1) = ai1;
  }
}

// ---------------- Stage B: Xp[hc][kx][ky][b][i] = sum_{h in chunk} e^{-2pi i kx h/256} G[b][ky][h][i]
// grid 1024 = b(8) x ky(16) x hc(8); 256 thr: i4 = t&15, kx = t>>4   (unchanged)
__global__ __launch_bounds__(256) void k_dft_h(const float* __restrict__ Gr, const float* __restrict__ Gi,
                                               float* __restrict__ Xpr, float* __restrict__ Xpi) {
  __shared__ float2 cs[256];
  __shared__ float gr[32 * 64];
  __shared__ float gi[32 * 64];
  const int t = threadIdx.x;
  {
    float s, c;
    sincospif((float)t * (1.0f / 128.0f), &s, &c);
    cs[t] = make_float2(c, s);
  }
  const int b = blockIdx.x >> 7;
  const int ky = (blockIdx.x >> 3) & 15;
  const int hc = blockIdx.x & 7;
  const float* grs = Gr + ((size_t)(b * NM + ky) * NH + hc * 32) * NC;
  const float* gis = Gi + ((size_t)(b * NM + ky) * NH + hc * 32) * NC;
#pragma unroll
  for (int r = 0; r < 2; ++r) {
    ((float4*)gr)[r * 256 + t] = ((const float4*)grs)[r * 256 + t];
    ((float4*)gi)[r * 256 + t] = ((const float4*)gis)[r * 256 + t];
  }
  __syncthreads();
  const int i4 = t & 15;
  const int kx = t >> 4;
  float4 xr = {0, 0, 0, 0}, xi = {0, 0, 0, 0};
  const float2 sv = cs[kx];
  const float str = sv.x, sti = -sv.y;
  const float2 tv = cs[(kx * hc * 32) & 255];
  float twr = tv.x, twi = -tv.y;
#pragma unroll 4
  for (int hh = 0; hh < 32; ++hh) {
    const float4 g_r = *(const float4*)&gr[hh * 64 + i4 * 4];
    const float4 g_i = *(const float4*)&gi[hh * 64 + i4 * 4];
    xr.x += twr * g_r.x - twi * g_i.x;
    xr.y += twr * g_r.y - twi * g_i.y;
    xr.z += twr * g_r.z - twi * g_i.z;
    xr.w += twr * g_r.w - twi * g_i.w;
    xi.x += twr * g_i.x + twi * g_r.x;
    xi.y += twr * g_i.y + twi * g_r.y;
    xi.z += twr * g_i.z + twi * g_r.z;
    xi.w += twr * g_i.w + twi * g_r.w;
    const float nr = twr * str - twi * sti;
    const float ni = twr * sti + twi * str;
    twr = nr; twi = ni;
  }
  const size_t o = ((size_t)((hc * NM + kx) * NM + ky) * NB + b) * NC + i4 * 4;
  *(float4*)(Xpr + o) = xr;
  *(float4*)(Xpi + o) = xi;
}

// ---------------- Stage C: om[b][kx][ky][o] = scale * sum_i (sum_hc Xp) * (wr + i wi)[kx][ky][i][o]
// grid 512 = kx(16) x ky(16) x oh(2); 256 thr: o = t&31, b = t>>5   (unchanged)
__global__ __launch_bounds__(256) void k_mix(const float* __restrict__ Xpr, const float* __restrict__ Xpi,
                                             const float* __restrict__ w_real, const float* __restrict__ w_imag,
                                             float2* __restrict__ om) {
  __shared__ float wr_s[64 * 32];
  __shared__ float wi_s[64 * 32];
  __shared__ float2 xc[8 * 64];
  const int t = threadIdx.x;
  const int kx = blockIdx.x >> 5;
  const int ky = (blockIdx.x >> 1) & 15;
  const int oh = blockIdx.x & 1;
  const size_t wb = (size_t)(kx * NM + ky) * 4096 + oh * 32;
#pragma unroll
  for (int r = 0; r < 2; ++r) {
    const int idx = r * 256 + t;  // 0..511
    const int i = idx >> 3, f = idx & 7;
    *(float4*)&wr_s[i * 32 + f * 4] = *(const float4*)(w_real + wb + (size_t)i * 64 + f * 4);
    *(float4*)&wi_s[i * 32 + f * 4] = *(const float4*)(w_imag + wb + (size_t)i * 64 + f * 4);
  }
#pragma unroll
  for (int r = 0; r < 2; ++r) {
    const int idx = r * 256 + t;  // idx = b*64 + i
    const size_t base = (size_t)(kx * NM + ky) * 512 + idx;
    float sr = 0.f, si = 0.f;
#pragma unroll
    for (int hc = 0; hc < 8; ++hc) {
      sr += Xpr[base + (size_t)hc * 131072];
      si += Xpi[base + (size_t)hc * 131072];
    }
    xc[idx] = make_float2(sr, si);
  }
  __syncthreads();
  const int o = t & 31;
  const int b = t >> 5;
  float r0 = 0.f, i0 = 0.f;
#pragma unroll 8
  for (int i = 0; i < 64; ++i) {
    const float2 xv = xc[b * 64 + i];
    const float wrv = wr_s[i * 32 + o];
    const float wiv = wi_s[i * 32 + o];
    r0 += xv.x * wrv - xv.y * wiv;
    i0 += xv.x * wiv + xv.y * wrv;
  }
  const float sc = (ky == 0 ? 1.0f : 2.0f) * (0.02f / 65536.0f);
  om[((size_t)(b * NM + kx) * NM + ky) * NO + oh * 32 + o] = make_float2(r0 * sc, i0 * sc);
}

// ---------------- Fused Stage D+E:
// Phase 1: Zs[kx][o] = sum_ky om[b][kx][ky][o] e^{+2pi i ky w/256}   (into LDS)
// Phase 2 (h-symmetric): accA = sum_kx zr*cos, accB = sum_kx zi*sin for
//   hA in [0,128); out[hA] = accA-accB, out[256-hA] = accA+accB.
//   h=0: accB==0 automatically (theta=0). h=128: accC = sum_kx (-1)^kx zr,
//   computed by the hg==0 lane group.
// grid 2048 = b(8) x w(256); 256 thr.
#define ZLD 72  // LDS stride (floats) per kx: 16-B aligned, breaks 256-B bank repeat
__global__ __launch_bounds__(256) void k_idft_we(const float2* __restrict__ om, float* __restrict__ out) {
  __shared__ float2 cs[256];
  __shared__ float zre[NM * ZLD];
  __shared__ float zim[NM * ZLD];
  const int t = threadIdx.x;
  {
    float s, c;
    sincospif((float)t * (1.0f / 128.0f), &s, &c);
    cs[t] = make_float2(c, s);
  }
  const int b = blockIdx.x >> 8;
  const int w = blockIdx.x & 255;
  __syncthreads();  // cs ready

  // ---- phase 1: inverse DFT over ky for this w
  {
    const int kx = t >> 4;
    const int og = t & 15;
    const float2* mp = om + ((size_t)(b * NM + kx) * NM) * NO + og * 4;
    float zr[4] = {0, 0, 0, 0}, zi[4] = {0, 0, 0, 0};
    const float2 st = cs[w];
    float twr = 1.0f, twi = 0.0f;
#pragma unroll
    for (int ky = 0; ky < NM; ++ky) {
      const float2 m0 = mp[(size_t)ky * NO + 0];
      const float2 m1 = mp[(size_t)ky * NO + 1];
      const float2 m2 = mp[(size_t)ky * NO + 2];
      const float2 m3 = mp[(size_t)ky * NO + 3];
      zr[0] += twr * m0.x - twi * m0.y; zi[0] += twr * m0.y + twi * m0.x;
      zr[1] += twr * m1.x - twi * m1.y; zi[1] += twr * m1.y + twi * m1.x;
      zr[2] += twr * m2.x - twi * m2.y; zi[2] += twr * m2.y + twi * m2.x;
      zr[3] += twr * m3.x - twi * m3.y; zi[3] += twr * m3.y + twi * m3.x;
      const float nr = twr * st.x - twi * st.y;
      const float ni = twr * st.y + twi * st.x;
      twr = nr; twi = ni;
    }
    *(float4*)&zre[kx * ZLD + og * 4] = make_float4(zr[0], zr[1], zr[2], zr[3]);
    *(float4*)&zim[kx * ZLD + og * 4] = make_float4(zi[0], zi[1], zi[2], zi[3]);
  }
  __syncthreads();

  // ---- phase 2: inverse DFT over kx (real part), h-conjugate-symmetric
  const int i4 = t & 15;   // 4 output channels
  const int hg = t >> 4;   // 0..15: hA = hg*8 + j, j = 0..7
  float4 accA[8], accB[8], accC;
#pragma unroll
  for (int j = 0; j < 8; ++j) {
    accA[j] = make_float4(0, 0, 0, 0);
    accB[j] = make_float4(0, 0, 0, 0);
  }
  accC = make_float4(0, 0, 0, 0);
#pragma unroll 4
  for (int kx = 0; kx < 16; ++kx) {
    const float4 zr4 = *(const float4*)&zre[kx * ZLD + i4 * 4];
    const float4 zi4 = *(const float4*)&zim[kx * ZLD + i4 * 4];
    if (hg == 0) {  // h=128 accumulator: sum (-1)^kx * zr
      const float sgn = (kx & 1) ? -1.0f : 1.0f;
      accC.x += sgn * zr4.x; accC.y += sgn * zr4.y;
      accC.z += sgn * zr4.z; accC.w += sgn * zr4.w;
    }
    const float2 st = cs[kx];                    // step e^{+2pi i kx/256}
    const float2 t0 = cs[(kx * hg * 8) & 255];   // start at hA = hg*8
    float twr = t0.x, twi = t0.y;
#pragma unroll
    for (int j = 0; j < 8; ++j) {
      accA[j].x += twr * zr4.x; accA[j].y += twr * zr4.y;
      accA[j].z += twr * zr4.z; accA[j].w += twr * zr4.w;
      accB[j].x += twi * zi4.x; accB[j].y += twi * zi4.y;
      accB[j].z += twi * zi4.z; accB[j].w += twi * zi4.w;
      const float nr = twr * st.x - twi * st.y;
      const float ni = twr * st.y + twi * st.x;
      twr = nr; twi = ni;
    }
  }
  const size_t hstr = (size_t)NW * NO;
  float* ob = out + ((size_t)(b * NH) * NW + w) * NO + i4 * 4;
#pragma unroll
  for (int j = 0; j < 8; ++j) {
    const int hA = hg * 8 + j;
    const float4 lo = make_float4(accA[j].x - accB[j].x, accA[j].y - accB[j].y,
                                  accA[j].z - accB[j].z, accA[j].w - accB[j].w);
    *(float4*)(ob + (size_t)hA * hstr) = lo;
    if (hA != 0) {
      const float4 hi = make_float4(accA[j].x + accB[j].x, accA[j].y + accB[j].y,
                                    accA[j].z + accB[j].z, accA[j].w + accB[j].w);
      *(float4*)(ob + (size_t)(256 - hA) * hstr) = hi;
    }
  }
  if (hg == 0) {
    *(float4*)(ob + (size_t)128 * hstr) = accC;
  }
}

extern "C" void kernel_launch(void* const* d_in, const int* in_sizes, int n_in,
                              void* d_out, int out_size, void* d_ws, size_t ws_size,
                              hipStream_t stream) {
  const float* x = (const float*)d_in[0];
  const float* w_real = (const float*)d_in[1];
  const float* w_imag = (const float*)d_in[2];
  float* out = (float*)d_out;
  char* ws = (char*)d_ws;

  float* Gr = (float*)(ws);                 // 8 MiB  [b][ky][h][i]
  float* Gi = (float*)(ws + 8388608);       // 8 MiB
  float* Xpr = (float*)(ws + 16777216);     // 4 MiB  [hc][kx][ky][b][i]
  float* Xpi = (float*)(ws + 20971520);     // 4 MiB
  float2* om = (float2*)(ws + 25165824);    // 1 MiB  [b][kx][ky][o]

  k_dft_w<<<dim3(2048), dim3(256), 0, stream>>>(x, Gr, Gi);
  k_dft_h<<<dim3(1024), dim3(256), 0, stream>>>(Gr, Gi, Xpr, Xpi);
  k_mix<<<dim3(512), dim3(256), 0, stream>>>(Xpr, Xpi, w_real, w_imag, om);
  k_idft_we<<<dim3(2048), dim3(256), 0, stream>>>(om, out);
}

// Round 4
// 276.038 us; speedup vs baseline: 1.1189x; 1.0309x over previous
//
#include <hip/hip_runtime.h>

// SpectralConv: B=8, H=256, W=256, C=64, modes 16x16, WIDTH=64, W_SCALE=0.02
// Round 5 (resubmit — previous bench failed at container acquisition, not kernel):
//  - Stage A: w<->w+128 pairing. e^{-2pi i ky(w+128)/256} = (-1)^ky e^{-2pi i ky w/256},
//    so even-ky accumulates s = x[w]+x[w+128], odd-ky accumulates d = x[w]-x[w+128],
//    over w in [0,128) only. Per w-pair: 8 adds + 16 FMA + 8 twiddle = 32 ops vs 48
//    -> A VALU ~20.5us -> ~13.9us, under its 20.6us HBM read floor.
//    Staging: paired 4 KiB chunks (w-chunk c, and +8192 floats), double-buffered;
//    LDS still 18 KiB -> 8 blocks/CU unchanged.
//  - Stages B, C, DE unchanged (DE is write-floor-bound after R4's h-symmetry).

#define NB 8
#define NH 256
#define NW 256
#define NC 64
#define NM 16
#define NO 64

// async global->LDS, 16 bytes per lane. LDS dest semantics (m97/m104):
// wave-uniform base + lane*16; pass a wave-uniform LDS pointer.
__device__ __forceinline__ void gload16(const float* g, float* l) {
  __builtin_amdgcn_global_load_lds(
      (const __attribute__((address_space(1))) void*)g,
      (__attribute__((address_space(3))) void*)l, 16, 0, 0);
}

// ---------------- Stage A: G[b][ky][h][i] = sum_w x[b,h,w,i] e^{-2pi i ky w/256}
// grid 2048 = b(8) x h(256); 256 thr: i4 = t&15, wh = (t>>4)&1, kyp = t>>5.
// ky0 = 2*kyp (even, uses s), ky1 = 2*kyp+1 (odd, uses d). w-halves combined
// via __shfl_xor(16) (partner lane in-wave).
__global__ __launch_bounds__(256) void k_dft_w(const float* __restrict__ x,
                                               float* __restrict__ Gr, float* __restrict__ Gi) {
  __shared__ float2 cs[256];
  __shared__ float xa[2][1024];  // w-chunk [16c, 16c+16): 16 w x 64 ch = 4 KiB
  __shared__ float xb[2][1024];  // paired chunk [16c+128, 16c+144)
  const int t = threadIdx.x;
  {
    float s, c;
    sincospif((float)t * (1.0f / 128.0f), &s, &c);
    cs[t] = make_float2(c, s);
  }
  const int b = blockIdx.x >> 8;
  const int h = blockIdx.x & 255;
  const float* row = x + (size_t)(b * NH + h) * (NW * NC);  // 64 KiB contiguous

  const int wv = t >> 6;  // wave id, uniform per wave
  // prologue: stage chunk 0 (4 KiB each = 1 round of 256 lanes x 16 B)
  {
    const float* g0 = row + t * 4;
    gload16(g0, &xa[0][wv * 256]);
    gload16(g0 + 8192, &xb[0][wv * 256]);  // +128 w = +8192 floats
  }

  const int i4 = t & 15;
  const int wh = (t >> 4) & 1;
  const int kyp = t >> 5;  // 0..7
  const int ky0 = kyp * 2, ky1 = ky0 + 1;

  __syncthreads();  // cs ready + chunk 0 landed (barrier drains vmcnt)

  const float2 s0v = cs[ky0], s1v = cs[ky1];
  const float s0r = s0v.x, s0i = -s0v.y, s1r = s1v.x, s1i = -s1v.y;

  float4 ar0 = {0, 0, 0, 0}, ai0 = {0, 0, 0, 0}, ar1 = {0, 0, 0, 0}, ai1 = {0, 0, 0, 0};
  int buf = 0;
  for (int c = 0; c < 8; ++c) {
    if (c < 7) {  // issue next-chunk async loads; they fly during compute
      const float* g0 = row + (c + 1) * 1024 + t * 4;
      gload16(g0, &xa[buf ^ 1][wv * 256]);
      gload16(g0 + 8192, &xb[buf ^ 1][wv * 256]);
    }
    const int w0 = c * 16 + wh * 8;
    const float2 u0 = cs[(ky0 * w0) & 255];
    const float2 u1 = cs[(ky1 * w0) & 255];
    float t0r = u0.x, t0i = -u0.y, t1r = u1.x, t1i = -u1.y;
    const float* pa = &xa[buf][wh * 512 + i4 * 4];
    const float* pb = &xb[buf][wh * 512 + i4 * 4];
#pragma unroll
    for (int ww = 0; ww < 8; ++ww) {
      const float4 va = *(const float4*)(pa + ww * 64);
      const float4 vb = *(const float4*)(pb + ww * 64);
      const float sx = va.x + vb.x, sy = va.y + vb.y, sz = va.z + vb.z, sw = va.w + vb.w;
      const float dx = va.x - vb.x, dy = va.y - vb.y, dz = va.z - vb.z, dw = va.w - vb.w;
      ar0.x += t0r * sx; ar0.y += t0r * sy; ar0.z += t0r * sz; ar0.w += t0r * sw;
      ai0.x += t0i * sx; ai0.y += t0i * sy; ai0.z += t0i * sz; ai0.w += t0i * sw;
      ar1.x += t1r * dx; ar1.y += t1r * dy; ar1.z += t1r * dz; ar1.w += t1r * dw;
      ai1.x += t1i * dx; ai1.y += t1i * dy; ai1.z += t1i * dz; ai1.w += t1i * dw;
      const float n0r = t0r * s0r - t0i * s0i, n0i = t0r * s0i + t0i * s0r;
      const float n1r = t1r * s1r - t1i * s1i, n1i = t1r * s1i + t1i * s1r;
      t0r = n0r; t0i = n0i; t1r = n1r; t1i = n1i;
    }
    __syncthreads();  // next chunk landed; all waves done reading current buf
    buf ^= 1;
  }

  // combine the two w-halves: partner lane = lane ^ 16 (same wave: wh is bit 4)
#define RED4(v)                                                         \
  v.x += __shfl_xor(v.x, 16); v.y += __shfl_xor(v.y, 16);               \
  v.z += __shfl_xor(v.z, 16); v.w += __shfl_xor(v.w, 16);
  RED4(ar0) RED4(ai0) RED4(ar1) RED4(ai1)
#undef RED4

  if (wh == 0) {
    const size_t g0 = ((size_t)(b * NM + ky0) * NH + h) * NC + i4 * 4;
    const size_t g1 = ((size_t)(b * NM + ky1) * NH + h) * NC + i4 * 4;
    *(float4*)(Gr + g0) = ar0; *(float4*)(Gi + g0) = ai0;
    *(float4*)(Gr + g1) = ar1; *(float4*)(Gi + g1) = ai1;
  }
}

// ---------------- Stage B: Xp[hc][kx][ky][b][i] = sum_{h in chunk} e^{-2pi i kx h/256} G[b][ky][h][i]
// grid 1024 = b(8) x ky(16) x hc(8); 256 thr: i4 = t&15, kx = t>>4   (unchanged)
__global__ __launch_bounds__(256) void k_dft_h(const float* __restrict__ Gr, const float* __restrict__ Gi,
                                               float* __restrict__ Xpr, float* __restrict__ Xpi) {
  __shared__ float2 cs[256];
  __shared__ float gr[32 * 64];
  __shared__ float gi[32 * 64];
  const int t = threadIdx.x;
  {
    float s, c;
    sincospif((float)t * (1.0f / 128.0f), &s, &c);
    cs[t] = make_float2(c, s);
  }
  const int b = blockIdx.x >> 7;
  const int ky = (blockIdx.x >> 3) & 15;
  const int hc = blockIdx.x & 7;
  const float* grs = Gr + ((size_t)(b * NM + ky) * NH + hc * 32) * NC;
  const float* gis = Gi + ((size_t)(b * NM + ky) * NH + hc * 32) * NC;
#pragma unroll
  for (int r = 0; r < 2; ++r) {
    ((float4*)gr)[r * 256 + t] = ((const float4*)grs)[r * 256 + t];
    ((float4*)gi)[r * 256 + t] = ((const float4*)gis)[r * 256 + t];
  }
  __syncthreads();
  const int i4 = t & 15;
  const int kx = t >> 4;
  float4 xr = {0, 0, 0, 0}, xi = {0, 0, 0, 0};
  const float2 sv = cs[kx];
  const float str = sv.x, sti = -sv.y;
  const float2 tv = cs[(kx * hc * 32) & 255];
  float twr = tv.x, twi = -tv.y;
#pragma unroll 4
  for (int hh = 0; hh < 32; ++hh) {
    const float4 g_r = *(const float4*)&gr[hh * 64 + i4 * 4];
    const float4 g_i = *(const float4*)&gi[hh * 64 + i4 * 4];
    xr.x += twr * g_r.x - twi * g_i.x;
    xr.y += twr * g_r.y - twi * g_i.y;
    xr.z += twr * g_r.z - twi * g_i.z;
    xr.w += twr * g_r.w - twi * g_i.w;
    xi.x += twr * g_i.x + twi * g_r.x;
    xi.y += twr * g_i.y + twi * g_r.y;
    xi.z += twr * g_i.z + twi * g_r.z;
    xi.w += twr * g_i.w + twi * g_r.w;
    const float nr = twr * str - twi * sti;
    const float ni = twr * sti + twi * str;
    twr = nr; twi = ni;
  }
  const size_t o = ((size_t)((hc * NM + kx) * NM + ky) * NB + b) * NC + i4 * 4;
  *(float4*)(Xpr + o) = xr;
  *(float4*)(Xpi + o) = xi;
}

// ---------------- Stage C: om[b][kx][ky][o] = scale * sum_i (sum_hc Xp) * (wr + i wi)[kx][ky][i][o]
// grid 512 = kx(16) x ky(16) x oh(2); 256 thr: o = t&31, b = t>>5   (unchanged)
__global__ __launch_bounds__(256) void k_mix(const float* __restrict__ Xpr, const float* __restrict__ Xpi,
                                             const float* __restrict__ w_real, const float* __restrict__ w_imag,
                                             float2* __restrict__ om) {
  __shared__ float wr_s[64 * 32];
  __shared__ float wi_s[64 * 32];
  __shared__ float2 xc[8 * 64];
  const int t = threadIdx.x;
  const int kx = blockIdx.x >> 5;
  const int ky = (blockIdx.x >> 1) & 15;
  const int oh = blockIdx.x & 1;
  const size_t wb = (size_t)(kx * NM + ky) * 4096 + oh * 32;
#pragma unroll
  for (int r = 0; r < 2; ++r) {
    const int idx = r * 256 + t;  // 0..511
    const int i = idx >> 3, f = idx & 7;
    *(float4*)&wr_s[i * 32 + f * 4] = *(const float4*)(w_real + wb + (size_t)i * 64 + f * 4);
    *(float4*)&wi_s[i * 32 + f * 4] = *(const float4*)(w_imag + wb + (size_t)i * 64 + f * 4);
  }
#pragma unroll
  for (int r = 0; r < 2; ++r) {
    const int idx = r * 256 + t;  // idx = b*64 + i
    const size_t base = (size_t)(kx * NM + ky) * 512 + idx;
    float sr = 0.f, si = 0.f;
#pragma unroll
    for (int hc = 0; hc < 8; ++hc) {
      sr += Xpr[base + (size_t)hc * 131072];
      si += Xpi[base + (size_t)hc * 131072];
    }
    xc[idx] = make_float2(sr, si);
  }
  __syncthreads();
  const int o = t & 31;
  const int b = t >> 5;
  float r0 = 0.f, i0 = 0.f;
#pragma unroll 8
  for (int i = 0; i < 64; ++i) {
    const float2 xv = xc[b * 64 + i];
    const float wrv = wr_s[i * 32 + o];
    const float wiv = wi_s[i * 32 + o];
    r0 += xv.x * wrv - xv.y * wiv;
    i0 += xv.x * wiv + xv.y * wrv;
  }
  const float sc = (ky == 0 ? 1.0f : 2.0f) * (0.02f / 65536.0f);
  om[((size_t)(b * NM + kx) * NM + ky) * NO + oh * 32 + o] = make_float2(r0 * sc, i0 * sc);
}

// ---------------- Fused Stage D+E:
// Phase 1: Zs[kx][o] = sum_ky om[b][kx][ky][o] e^{+2pi i ky w/256}   (into LDS)
// Phase 2 (h-symmetric): accA = sum_kx zr*cos, accB = sum_kx zi*sin for
//   hA in [0,128); out[hA] = accA-accB, out[256-hA] = accA+accB.
//   h=0: accB==0 automatically. h=128: accC = sum_kx (-1)^kx zr (hg==0 lanes).
// grid 2048 = b(8) x w(256); 256 thr.   (unchanged from R4)
#define ZLD 72  // LDS stride (floats) per kx: 16-B aligned, breaks 256-B bank repeat
__global__ __launch_bounds__(256) void k_idft_we(const float2* __restrict__ om, float* __restrict__ out) {
  __shared__ float2 cs[256];
  __shared__ float zre[NM * ZLD];
  __shared__ float zim[NM * ZLD];
  const int t = threadIdx.x;
  {
    float s, c;
    sincospif((float)t * (1.0f / 128.0f), &s, &c);
    cs[t] = make_float2(c, s);
  }
  const int b = blockIdx.x >> 8;
  const int w = blockIdx.x & 255;
  __syncthreads();  // cs ready

  // ---- phase 1: inverse DFT over ky for this w
  {
    const int kx = t >> 4;
    const int og = t & 15;
    const float2* mp = om + ((size_t)(b * NM + kx) * NM) * NO + og * 4;
    float zr[4] = {0, 0, 0, 0}, zi[4] = {0, 0, 0, 0};
    const float2 st = cs[w];
    float twr = 1.0f, twi = 0.0f;
#pragma unroll
    for (int ky = 0; ky < NM; ++ky) {
      const float2 m0 = mp[(size_t)ky * NO + 0];
      const float2 m1 = mp[(size_t)ky * NO + 1];
      const float2 m2 = mp[(size_t)ky * NO + 2];
      const float2 m3 = mp[(size_t)ky * NO + 3];
      zr[0] += twr * m0.x - twi * m0.y; zi[0] += twr * m0.y + twi * m0.x;
      zr[1] += twr * m1.x - twi * m1.y; zi[1] += twr * m1.y + twi * m1.x;
      zr[2] += twr * m2.x - twi * m2.y; zi[2] += twr * m2.y + twi * m2.x;
      zr[3] += twr * m3.x - twi * m3.y; zi[3] += twr * m3.y + twi * m3.x;
      const float nr = twr * st.x - twi * st.y;
      const float ni = twr * st.y + twi * st.x;
      twr = nr; twi = ni;
    }
    *(float4*)&zre[kx * ZLD + og * 4] = make_float4(zr[0], zr[1], zr[2], zr[3]);
    *(float4*)&zim[kx * ZLD + og * 4] = make_float4(zi[0], zi[1], zi[2], zi[3]);
  }
  __syncthreads();

  // ---- phase 2: inverse DFT over kx (real part), h-conjugate-symmetric
  const int i4 = t & 15;   // 4 output channels
  const int hg = t >> 4;   // 0..15: hA = hg*8 + j, j = 0..7
  float4 accA[8], accB[8], accC;
#pragma unroll
  for (int j = 0; j < 8; ++j) {
    accA[j] = make_float4(0, 0, 0, 0);
    accB[j] = make_float4(0, 0, 0, 0);
  }
  accC = make_float4(0, 0, 0, 0);
#pragma unroll 4
  for (int kx = 0; kx < 16; ++kx) {
    const float4 zr4 = *(const float4*)&zre[kx * ZLD + i4 * 4];
    const float4 zi4 = *(const float4*)&zim[kx * ZLD + i4 * 4];
    if (hg == 0) {  // h=128 accumulator: sum (-1)^kx * zr
      const float sgn = (kx & 1) ? -1.0f : 1.0f;
      accC.x += sgn * zr4.x; accC.y += sgn * zr4.y;
      accC.z += sgn * zr4.z; accC.w += sgn * zr4.w;
    }
    const float2 st = cs[kx];                    // step e^{+2pi i kx/256}
    const float2 t0 = cs[(kx * hg * 8) & 255];   // start at hA = hg*8
    float twr = t0.x, twi = t0.y;
#pragma unroll
    for (int j = 0; j < 8; ++j) {
      accA[j].x += twr * zr4.x; accA[j].y += twr * zr4.y;
      accA[j].z += twr * zr4.z; accA[j].w += twr * zr4.w;
      accB[j].x += twi * zi4.x; accB[j].y += twi * zi4.y;
      accB[j].z += twi * zi4.z; accB[j].w += twi * zi4.w;
      const float nr = twr * st.x - twi * st.y;
      const float ni = twr * st.y + twi * st.x;
      twr = nr; twi = ni;
    }
  }
  const size_t hstr = (size_t)NW * NO;
  float* ob = out + ((size_t)(b * NH) * NW + w) * NO + i4 * 4;
#pragma unroll
  for (int j = 0; j < 8; ++j) {
    const int hA = hg * 8 + j;
    const float4 lo = make_float4(accA[j].x - accB[j].x, accA[j].y - accB[j].y,
                                  accA[j].z - accB[j].z, accA[j].w - accB[j].w);
    *(float4*)(ob + (size_t)hA * hstr) = lo;
    if (hA != 0) {
      const float4 hi = make_float4(accA[j].x + accB[j].x, accA[j].y + accB[j].y,
                                    accA[j].z + accB[j].z, accA[j].w + accB[j].w);
      *(float4*)(ob + (size_t)(256 - hA) * hstr) = hi;
    }
  }
  if (hg == 0) {
    *(float4*)(ob + (size_t)128 * hstr) = accC;
  }
}

extern "C" void kernel_launch(void* const* d_in, const int* in_sizes, int n_in,
                              void* d_out, int out_size, void* d_ws, size_t ws_size,
                              hipStream_t stream) {
  const float* x = (const float*)d_in[0];
  const float* w_real = (const float*)d_in[1];
  const float* w_imag = (const float*)d_in[2];
  float* out = (float*)d_out;
  char* ws = (char*)d_ws;

  float* Gr = (float*)(ws);                 // 8 MiB  [b][ky][h][i]
  float* Gi = (float*)(ws + 8388608);       // 8 MiB
  float* Xpr = (float*)(ws + 16777216);     // 4 MiB  [hc][kx][ky][b][i]
  float* Xpi = (float*)(ws + 20971520);     // 4 MiB
  float2* om = (float2*)(ws + 25165824);    // 1 MiB  [b][kx][ky][o]

  k_dft_w<<<dim3(2048), dim3(256), 0, stream>>>(x, Gr, Gi);
  k_dft_h<<<dim3(1024), dim3(256), 0, stream>>>(Gr, Gi, Xpr, Xpi);
  k_mix<<<dim3(512), dim3(256), 0, stream>>>(Xpr, Xpi, w_real, w_imag, om);
  k_idft_we<<<dim3(2048), dim3(256), 0, stream>>>(om, out);
}